// Round 4
// baseline (313.483 us; speedup 1.0000x reference)
//
#include <hip/hip_runtime.h>

// bf16 MFMA fragment types (per guide §3)
typedef short bf16x8 __attribute__((ext_vector_type(8)));
typedef float f32x4  __attribute__((ext_vector_type(4)));

__device__ __forceinline__ unsigned short f2bf(float f) {
    union { float f; unsigned int u; } v; v.f = f;
    unsigned int r = v.u + 0x7fffu + ((v.u >> 16) & 1u);  // RNE, inputs never NaN
    return (unsigned short)(r >> 16);
}

__device__ __forceinline__ unsigned int pack_bf16(float a, float b) {
#if __has_builtin(__builtin_amdgcn_cvt_pk_bf16_f32)
    typedef __bf16 bf16x2 __attribute__((ext_vector_type(2)));
    bf16x2 p = __builtin_amdgcn_cvt_pk_bf16_f32(a, b);
    union { bf16x2 v; unsigned int u; } c; c.v = p;
    return c.u;
#else
    return (unsigned int)f2bf(a) | ((unsigned int)f2bf(b) << 16);
#endif
}

__device__ __forceinline__ float fast_sigmoid8(float x) {
    float e = __expf(-0.125f * x);
    return __builtin_amdgcn_rcpf(1.0f + e);
}

// ---------------------------------------------------------------------------
// prep: per (b, fixedIdx) block: slab[k][c] = src[b, ...], compute
//   Q[n=bx*64+c][j] -> Qg  [b][4096][64] bf16 (row-major)
//   V[n][j]         -> Vtg [b][64][4096] bf16 (transposed)
// height stage: bx=w, k=h (sK=4096,sF=64); width stage: bx=h, k=w (sK=64,sF=4096)
// ---------------------------------------------------------------------------
__global__ __launch_bounds__(256) void prep_kernel(
    const float* __restrict__ src,
    const float* __restrict__ wq, const float* __restrict__ bq,
    const float* __restrict__ wv, const float* __restrict__ bv,
    unsigned short* __restrict__ Qg, unsigned short* __restrict__ Vtg,
    float* __restrict__ x1out, int sK, int sF)
{
    __shared__ float slab[64][65];
    __shared__ float wqs[4096];
    __shared__ float wvs[4096];

    const int t  = threadIdx.x;
    const int bx = blockIdx.x, b = blockIdx.y;

    {   // stage weights
        const float4* wq4 = (const float4*)wq;
        const float4* wv4 = (const float4*)wv;
        float4* q4 = (float4*)wqs; float4* v4 = (float4*)wvs;
        #pragma unroll
        for (int i = 0; i < 4; ++i) {
            q4[i*256 + t] = wq4[i*256 + t];
            v4[i*256 + t] = wv4[i*256 + t];
        }
    }
    {   // stage slab
        const int k = t >> 2, c0 = (t & 3) << 4;
        const size_t sb = (size_t)b*262144 + (size_t)k*sK + (size_t)bx*sF + c0;
        #pragma unroll
        for (int i = 0; i < 4; ++i) {
            float4 v = *(const float4*)&src[sb + i*4];
            *(float4*)&slab[k][c0 + i*4] = v;
            if (x1out) *(float4*)&x1out[sb + i*4] = v;
        }
    }
    __syncthreads();

    const int c = t & 63, jg = t >> 6;
    float qa[16], va[16];
    #pragma unroll
    for (int jj = 0; jj < 16; ++jj) { qa[jj] = bq[jg*16+jj]; va[jj] = bv[jg*16+jj]; }
    for (int k = 0; k < 64; ++k) {
        const float xv = slab[k][c];
        const float* wqr = &wqs[k*64 + jg*16];
        const float* wvr = &wvs[k*64 + jg*16];
        #pragma unroll
        for (int jj = 0; jj < 16; ++jj) {
            qa[jj] += xv * wqr[jj];
            va[jj] += xv * wvr[jj];
        }
    }
    const int token = bx*64 + c;
    union { unsigned short s[16]; uint4 v[2]; } qp, vp;
    #pragma unroll
    for (int jj = 0; jj < 16; ++jj) { qp.s[jj] = f2bf(qa[jj]); vp.s[jj] = f2bf(va[jj]); }
    const size_t qoff = ((size_t)b*4096 + token)*64 + jg*16;
    *(uint4*)&Qg[qoff]     = qp.v[0];
    *(uint4*)&Qg[qoff + 8] = qp.v[1];
    #pragma unroll
    for (int jj = 0; jj < 16; ++jj)
        Vtg[((size_t)b*64 + jg*16 + jj)*4096 + token] = vp.s[jj];
}

// ---------------------------------------------------------------------------
// attn v4: BARRIER-FREE. K/V MFMA fragments are loaded directly from global
// (K A-frag = 16B runs of Qg rows; V B-frag = 16B runs of Vtg rows) — L1/L2
// serve them, all 4 waves of a block reuse the same lines. LDS only holds the
// wave-private S transpose (no __syncthreads in the kernel at all). Each wave
// owns 32 queries (2 query-groups sharing each K/V fragment: 32 MFMA per 16KB
// loaded). Explicit register prefetch of the next key-tile hides L2 latency.
// ---------------------------------------------------------------------------
__global__ __launch_bounds__(256, 2) void attn_kernel(
    const unsigned short* __restrict__ Qg,
    const unsigned short* __restrict__ Vtg,
    const float* __restrict__ gate,
    float* __restrict__ dst,
    const float* __restrict__ p,
    int axis)
{
    __shared__ unsigned int Ss[128][36];   // 4 waves x 32 query rows, 144B stride

    const int t = threadIdx.x;
    const int mb = blockIdx.x;             // 128-query tile
    const int b = blockIdx.y, ksplit = blockIdx.z;
    const int lane = t & 63, w = t >> 6;
    const int quad = lane >> 4, l16 = lane & 15;

    const unsigned short* Qbase = Qg  + (size_t)b*262144;
    const unsigned short* Vbase = Vtg + (size_t)b*262144;

    // Q B-frags for this wave's two query groups: B[k=d][n=query=l16]
    bf16x8 qb[2][2];
    #pragma unroll
    for (int qg = 0; qg < 2; ++qg) {
        const unsigned short* qrow = Qbase + (size_t)(mb*128 + w*32 + qg*16 + l16)*64;
        qb[qg][0] = *(const bf16x8*)&qrow[quad*8];
        qb[qg][1] = *(const bf16x8*)&qrow[32 + quad*8];
    }

    f32x4 y[2][4];
    #pragma unroll
    for (int qg = 0; qg < 2; ++qg)
        #pragma unroll
        for (int db = 0; db < 4; ++db)
            y[qg][db] = (f32x4){0.f, 0.f, 0.f, 0.f};

    // per-lane fragment base pointers
    const unsigned short* kbase = Qbase + (size_t)l16*64   + quad*8;  // + key*64 + s*32
    const unsigned short* vbase = Vbase + (size_t)l16*4096 + quad*8;  // + db*65536 + key + s*32

    // current-tile fragments
    bf16x8 ka[2][4], va[2][4];
    {
        const int key0 = ksplit*1024;
        #pragma unroll
        for (int s = 0; s < 2; ++s)
            #pragma unroll
            for (int u = 0; u < 4; ++u)
                ka[s][u] = *(const bf16x8*)(kbase + (size_t)(key0 + u*16)*64 + s*32);
        #pragma unroll
        for (int s = 0; s < 2; ++s)
            #pragma unroll
            for (int db = 0; db < 4; ++db)
                va[s][db] = *(const bf16x8*)(vbase + (size_t)db*65536 + key0 + s*32);
    }

    const int srow0 = w*32 + l16;
    const unsigned short* SsS = (const unsigned short*)&Ss[0][0];

    #pragma unroll 2
    for (int kb = 0; kb < 16; ++kb) {
        // prefetch next tile (clamped at the end: reloads current, in-bounds)
        const int keyn = ksplit*1024 + (kb < 15 ? (kb + 1)*64 : kb*64);
        bf16x8 nk[2][4], nv[2][4];
        #pragma unroll
        for (int s = 0; s < 2; ++s)
            #pragma unroll
            for (int u = 0; u < 4; ++u)
                nk[s][u] = *(const bf16x8*)(kbase + (size_t)(keyn + u*16)*64 + s*32);
        #pragma unroll
        for (int s = 0; s < 2; ++s)
            #pragma unroll
            for (int db = 0; db < 4; ++db)
                nv[s][db] = *(const bf16x8*)(vbase + (size_t)db*65536 + keyn + s*32);

        #pragma unroll
        for (int qg = 0; qg < 2; ++qg) {
            // T_u = K_u · Q_qg^T (A = K rows, B = Q rows), accumulate over d
            f32x4 tacc[4];
            #pragma unroll
            for (int u = 0; u < 4; ++u) tacc[u] = (f32x4){0.f, 0.f, 0.f, 0.f};
            #pragma unroll
            for (int s = 0; s < 2; ++s)
                #pragma unroll
                for (int u = 0; u < 4; ++u)
                    tacc[u] = __builtin_amdgcn_mfma_f32_16x16x32_bf16(ka[s][u], qb[qg][s], tacc[u], 0,0,0);

            // lane holds T[key=u*16+quad*4+r][query=l16] -> sigmoid, pack, b64 store
            const int srow = srow0 + qg*16;
            #pragma unroll
            for (int u = 0; u < 4; ++u) {
                uint2 pk;
                pk.x = pack_bf16(fast_sigmoid8(tacc[u][0]), fast_sigmoid8(tacc[u][1]));
                pk.y = pack_bf16(fast_sigmoid8(tacc[u][2]), fast_sigmoid8(tacc[u][3]));
                *(uint2*)&Ss[srow][u*8 + quad*2] = pk;
            }
            // wave-private rows: in-wave lgkmcnt ordering, no barrier needed

            // Y += S·V : A = S[m=query=l16][k=key], B = Vt rows
            #pragma unroll
            for (int s = 0; s < 2; ++s) {
                bf16x8 sa = *(const bf16x8*)&SsS[(size_t)srow*72 + s*32 + quad*8];
                #pragma unroll
                for (int db = 0; db < 4; ++db)
                    y[qg][db] = __builtin_amdgcn_mfma_f32_16x16x32_bf16(sa, va[s][db], y[qg][db], 0,0,0);
            }
        }

        // rotate prefetched fragments in
        #pragma unroll
        for (int s = 0; s < 2; ++s)
            #pragma unroll
            for (int u = 0; u < 4; ++u) { ka[s][u] = nk[s][u]; va[s][u] = nv[s][u]; }
    }

    // epilogue: query token = bx*64 + c with bx = 2*mb + (w>>1), c = (w&1)*32 + qg*16 + quad*4 + r
    const float g = gate[0];
    const int bx = 2*mb + (w >> 1);
    if (axis == 0) {
        #pragma unroll
        for (int qg = 0; qg < 2; ++qg)
            #pragma unroll
            for (int db = 0; db < 4; ++db) {
                const int d = db*16 + l16;                       // = h
                #pragma unroll
                for (int r = 0; r < 4; ++r) {
                    const int c = (w & 1)*32 + qg*16 + quad*4 + r;
                    atomicAdd(&dst[(((size_t)b*64 + d)*64 + bx)*64 + c], g * y[qg][db][r]);
                }
            }
    } else {
        #pragma unroll
        for (int qg = 0; qg < 2; ++qg)
            #pragma unroll
            for (int db = 0; db < 4; ++db) {
                const int d = db*16 + l16;                       // = w-coord
                const float pv = p[(b*64 + bx)*64 + d] * g;      // pixel (b, h=bx, w=d)
                #pragma unroll
                for (int r = 0; r < 4; ++r) {
                    const int c = (w & 1)*32 + qg*16 + quad*4 + r;
                    atomicAdd(&dst[(((size_t)b*64 + bx)*64 + d)*64 + c], pv * y[qg][db][r]);
                }
            }
    }
}

// p[pix] = conv_b + sum_nc (1 - sigmoid(predict[pix][nc])) * conv_w[nc]
__global__ __launch_bounds__(256) void pred_kernel(
    const float* __restrict__ predict, const float* __restrict__ conv_w,
    const float* __restrict__ conv_b, float* __restrict__ p)
{
    const int pix = blockIdx.x * 256 + threadIdx.x;   // 16384 pixels
    const float* row = predict + (size_t)pix * 19;
    float s = conv_b[0];
    #pragma unroll
    for (int i = 0; i < 19; ++i) {
        float sg = 1.0f / (1.0f + __expf(-row[i]));
        s += (1.0f - sg) * conv_w[i];
    }
    p[pix] = s;
}

// out = p * (feature + x1); attn width stage then adds p*w_gate*Yw
__global__ __launch_bounds__(256) void prefill_kernel(
    const float* __restrict__ feature, const float* __restrict__ x1,
    const float* __restrict__ p, float* __restrict__ out)
{
    const int i4 = blockIdx.x * 256 + threadIdx.x;    // 262144 float4s
    float4 f = ((const float4*)feature)[i4];
    float4 x = ((const float4*)x1)[i4];
    const float pv = p[i4 >> 4];                      // 64 floats per pixel
    float4 o;
    o.x = pv * (f.x + x.x);
    o.y = pv * (f.y + x.y);
    o.z = pv * (f.z + x.z);
    o.w = pv * (f.w + x.w);
    ((float4*)out)[i4] = o;
}

extern "C" void kernel_launch(void* const* d_in, const int* in_sizes, int n_in,
                              void* d_out, int out_size, void* d_ws, size_t ws_size,
                              hipStream_t stream) {
    const float* feature = (const float*)d_in[0];
    const float* predict = (const float*)d_in[1];
    const float* hq_w = (const float*)d_in[2];
    const float* hq_b = (const float*)d_in[3];
    const float* hv_w = (const float*)d_in[4];
    const float* hv_b = (const float*)d_in[5];
    const float* wq_w = (const float*)d_in[6];
    const float* wq_b = (const float*)d_in[7];
    const float* wv_w = (const float*)d_in[8];
    const float* wv_b = (const float*)d_in[9];
    const float* h_gate = (const float*)d_in[10];
    const float* w_gate = (const float*)d_in[11];
    const float* conv_w = (const float*)d_in[12];
    const float* conv_b = (const float*)d_in[13];
    float* out = (float*)d_out;

    // workspace layout (8.06 MiB total)
    char* ws = (char*)d_ws;
    unsigned short* Qg  = (unsigned short*)(ws);                    // 2 MiB
    unsigned short* Vtg = (unsigned short*)(ws + (2u << 20));       // 2 MiB
    float*          x1  = (float*)(ws + (4u << 20));                // 4 MiB
    float*          p   = (float*)(ws + (8u << 20));                // 64 KiB

    dim3 blk(256);
    // height stage: Q/V from feature; also x1 = feature
    prep_kernel<<<dim3(64, 4), blk, 0, stream>>>(feature, hq_w, hq_b, hv_w, hv_b,
                                                 Qg, Vtg, x1, 4096, 64);
    // x1 += h_gate * Yh
    attn_kernel<<<dim3(32, 4, 4), blk, 0, stream>>>(Qg, Vtg, h_gate, x1, nullptr, 0);
    // gate map
    pred_kernel<<<dim3(64), blk, 0, stream>>>(predict, conv_w, conv_b, p);
    // width stage: Q/V from x1
    prep_kernel<<<dim3(64, 4), blk, 0, stream>>>(x1, wq_w, wq_b, wv_w, wv_b,
                                                 Qg, Vtg, nullptr, 64, 4096);
    // out = p * (feature + x1)
    prefill_kernel<<<dim3(1024), blk, 0, stream>>>(feature, x1, p, out);
    // out += p * w_gate * Yw
    attn_kernel<<<dim3(32, 4, 4), blk, 0, stream>>>(Qg, Vtg, w_gate, out, p, 1);
}

// Round 5
// 279.448 us; speedup vs baseline: 1.1218x; 1.1218x over previous
//
#include <hip/hip_runtime.h>

// bf16 MFMA fragment types (per guide §3)
typedef short bf16x8 __attribute__((ext_vector_type(8)));
typedef float f32x4  __attribute__((ext_vector_type(4)));

#define LDP 72  // padded bf16 LDS row (64 + 8 shorts): 144B stride, 16B-aligned

__device__ __forceinline__ unsigned short f2bf(float f) {
    union { float f; unsigned int u; } v; v.f = f;
    unsigned int r = v.u + 0x7fffu + ((v.u >> 16) & 1u);  // RNE, inputs never NaN
    return (unsigned short)(r >> 16);
}

__device__ __forceinline__ unsigned int pack_bf16(float a, float b) {
#if __has_builtin(__builtin_amdgcn_cvt_pk_bf16_f32)
    typedef __bf16 bf16x2 __attribute__((ext_vector_type(2)));
    bf16x2 p = __builtin_amdgcn_cvt_pk_bf16_f32(a, b);
    union { bf16x2 v; unsigned int u; } c; c.v = p;
    return c.u;
#else
    return (unsigned int)f2bf(a) | ((unsigned int)f2bf(b) << 16);
#endif
}

__device__ __forceinline__ float fast_sigmoid8(float x) {
    // sigmoid(x/8) = 1/(1+2^(x * -0.125*log2(e)))
    float e = __builtin_exp2f(x * -0.180336880f);
    return __builtin_amdgcn_rcpf(1.0f + e);
}

// ---------------------------------------------------------------------------
// prep: per (b, fixedIdx) block: slab[k][c] = src[b, ...], compute
//   Q[n=bx*64+c][j] -> Qg  [b][4096][64] bf16 (row-major)
//   V[n][j]         -> Vtg [b][64][4096] bf16 (transposed)
// height stage: bx=w, k=h (sK=4096,sF=64); width stage: bx=h, k=w (sK=64,sF=4096)
// ---------------------------------------------------------------------------
__global__ __launch_bounds__(256) void prep_kernel(
    const float* __restrict__ src,
    const float* __restrict__ wq, const float* __restrict__ bq,
    const float* __restrict__ wv, const float* __restrict__ bv,
    unsigned short* __restrict__ Qg, unsigned short* __restrict__ Vtg,
    float* __restrict__ x1out, int sK, int sF)
{
    __shared__ float slab[64][65];
    __shared__ float wqs[4096];
    __shared__ float wvs[4096];

    const int t  = threadIdx.x;
    const int bx = blockIdx.x, b = blockIdx.y;

    {   // stage weights
        const float4* wq4 = (const float4*)wq;
        const float4* wv4 = (const float4*)wv;
        float4* q4 = (float4*)wqs; float4* v4 = (float4*)wvs;
        #pragma unroll
        for (int i = 0; i < 4; ++i) {
            q4[i*256 + t] = wq4[i*256 + t];
            v4[i*256 + t] = wv4[i*256 + t];
        }
    }
    {   // stage slab
        const int k = t >> 2, c0 = (t & 3) << 4;
        const size_t sb = (size_t)b*262144 + (size_t)k*sK + (size_t)bx*sF + c0;
        #pragma unroll
        for (int i = 0; i < 4; ++i) {
            float4 v = *(const float4*)&src[sb + i*4];
            *(float4*)&slab[k][c0 + i*4] = v;
            if (x1out) *(float4*)&x1out[sb + i*4] = v;
        }
    }
    __syncthreads();

    const int c = t & 63, jg = t >> 6;
    float qa[16], va[16];
    #pragma unroll
    for (int jj = 0; jj < 16; ++jj) { qa[jj] = bq[jg*16+jj]; va[jj] = bv[jg*16+jj]; }
    for (int k = 0; k < 64; ++k) {
        const float xv = slab[k][c];
        const float* wqr = &wqs[k*64 + jg*16];
        const float* wvr = &wvs[k*64 + jg*16];
        #pragma unroll
        for (int jj = 0; jj < 16; ++jj) {
            qa[jj] += xv * wqr[jj];
            va[jj] += xv * wvr[jj];
        }
    }
    const int token = bx*64 + c;
    union { unsigned short s[16]; uint4 v[2]; } qp, vp;
    #pragma unroll
    for (int jj = 0; jj < 16; ++jj) { qp.s[jj] = f2bf(qa[jj]); vp.s[jj] = f2bf(va[jj]); }
    const size_t qoff = ((size_t)b*4096 + token)*64 + jg*16;
    *(uint4*)&Qg[qoff]     = qp.v[0];
    *(uint4*)&Qg[qoff + 8] = qp.v[1];
    #pragma unroll
    for (int jj = 0; jj < 16; ++jj)
        Vtg[((size_t)b*64 + jg*16 + jj)*4096 + token] = vp.s[jj];
}

// ---------------------------------------------------------------------------
// attn v5: r3's LDS staging + ping-pong + reg-prefetch, PLUS r4's 32-queries-
// per-wave blocking (qg=2). K-frags (8 b128) and V-frags (8 b128) are read
// from LDS once per iteration and reused by BOTH query groups -> LDS reads
// per query ~halved vs r3. Block = 4 waves = 128 queries; 16 key-tiles of 64.
// Score tile transposed (T = K·Q^T) -> sigmoid -> packed b64 into wave-private
// Ss rows (no barrier for the S round-trip); one __syncthreads per iteration.
// ---------------------------------------------------------------------------
__global__ __launch_bounds__(256) void attn_kernel(
    const unsigned short* __restrict__ Qg,
    const unsigned short* __restrict__ Vtg,
    const float* __restrict__ gate,
    float* __restrict__ dst,
    const float* __restrict__ p,
    int axis)
{
    __shared__ unsigned short Ksh[2][64][LDP];
    __shared__ unsigned short Vts[2][64][LDP];
    __shared__ unsigned int   Ss [128][LDP/2];   // 4 waves x 32 query rows

    const int t = threadIdx.x;
    const int mb = blockIdx.x;                   // 128-query tile
    const int b = blockIdx.y, ksplit = blockIdx.z;
    const int lane = t & 63, w = t >> 6;
    const int quad = lane >> 4, l16 = lane & 15;

    const unsigned short* Qbase = Qg  + (size_t)b*262144;
    const unsigned short* Vbase = Vtg + (size_t)b*262144;

    // Q B-frags for this wave's two query groups: B[k=d][n=query=l16]
    bf16x8 qb[2][2];
    #pragma unroll
    for (int qg = 0; qg < 2; ++qg) {
        const unsigned short* qrow = Qbase + (size_t)(mb*128 + w*32 + qg*16 + l16)*64;
        qb[qg][0] = *(const bf16x8*)&qrow[quad*8];
        qb[qg][1] = *(const bf16x8*)&qrow[32 + quad*8];
    }

    f32x4 y[2][4];
    #pragma unroll
    for (int qg = 0; qg < 2; ++qg)
        #pragma unroll
        for (int db = 0; db < 4; ++db)
            y[qg][db] = (f32x4){0.f, 0.f, 0.f, 0.f};

    const int lrow = t >> 2, loff = (t & 3) << 4;
    const unsigned short* SsS = (const unsigned short*)&Ss[0][0];

    {   // prologue: stage tile 0 into buffer 0
        const int key0 = ksplit*1024;
        const uint4* gk = (const uint4*)(Qbase + (size_t)(key0 + lrow)*64 + loff);
        uint4 k0 = gk[0], k1 = gk[1];
        const uint4* gv = (const uint4*)(Vbase + (size_t)lrow*4096 + key0 + loff);
        uint4 v0 = gv[0], v1 = gv[1];
        *(uint4*)&Ksh[0][lrow][loff]     = k0;
        *(uint4*)&Ksh[0][lrow][loff + 8] = k1;
        *(uint4*)&Vts[0][lrow][loff]     = v0;
        *(uint4*)&Vts[0][lrow][loff + 8] = v1;
    }
    __syncthreads();

    for (int kb = 0; kb < 16; ++kb) {
        const int cur = kb & 1, nxt = cur ^ 1;

        // prefetch next tile into registers (clamped; stays in flight all iter)
        const int keyn = ksplit*1024 + (kb < 15 ? (kb + 1)*64 : kb*64);
        uint4 nk0, nk1, nv0, nv1;
        {
            const uint4* gk = (const uint4*)(Qbase + (size_t)(keyn + lrow)*64 + loff);
            nk0 = gk[0]; nk1 = gk[1];
            const uint4* gv = (const uint4*)(Vbase + (size_t)lrow*4096 + keyn + loff);
            nv0 = gv[0]; nv1 = gv[1];
        }

        // K A-frags once, reused by both query groups
        bf16x8 ka[2][4];
        #pragma unroll
        for (int s = 0; s < 2; ++s)
            #pragma unroll
            for (int u = 0; u < 4; ++u)
                ka[s][u] = *(const bf16x8*)&Ksh[cur][u*16 + l16][s*32 + quad*8];

        // T = K·Q^T for both query groups; sigmoid; pack to wave-private Ss rows
        #pragma unroll
        for (int qg = 0; qg < 2; ++qg) {
            f32x4 tacc[4];
            #pragma unroll
            for (int u = 0; u < 4; ++u) tacc[u] = (f32x4){0.f, 0.f, 0.f, 0.f};
            #pragma unroll
            for (int s = 0; s < 2; ++s)
                #pragma unroll
                for (int u = 0; u < 4; ++u)
                    tacc[u] = __builtin_amdgcn_mfma_f32_16x16x32_bf16(ka[s][u], qb[qg][s], tacc[u], 0,0,0);

            const int srow = w*32 + qg*16 + l16;
            #pragma unroll
            for (int u = 0; u < 4; ++u) {
                uint2 pk;
                pk.x = pack_bf16(fast_sigmoid8(tacc[u][0]), fast_sigmoid8(tacc[u][1]));
                pk.y = pack_bf16(fast_sigmoid8(tacc[u][2]), fast_sigmoid8(tacc[u][3]));
                *(uint2*)&Ss[srow][u*8 + quad*2] = pk;
            }
        }
        // wave-private Ss rows: in-wave lgkmcnt ordering, no barrier needed

        // Y += S·V : V B-frags read once per s, reused by both query groups
        #pragma unroll
        for (int s = 0; s < 2; ++s) {
            bf16x8 vb[4];
            #pragma unroll
            for (int db = 0; db < 4; ++db)
                vb[db] = *(const bf16x8*)&Vts[cur][db*16 + l16][s*32 + quad*8];
            #pragma unroll
            for (int qg = 0; qg < 2; ++qg) {
                bf16x8 sa = *(const bf16x8*)&SsS[(size_t)(w*32 + qg*16 + l16)*LDP + s*32 + quad*8];
                #pragma unroll
                for (int db = 0; db < 4; ++db)
                    y[qg][db] = __builtin_amdgcn_mfma_f32_16x16x32_bf16(sa, vb[db], y[qg][db], 0,0,0);
            }
        }

        // drain prefetch into the idle buffer
        if (kb < 15) {
            *(uint4*)&Ksh[nxt][lrow][loff]     = nk0;
            *(uint4*)&Ksh[nxt][lrow][loff + 8] = nk1;
            *(uint4*)&Vts[nxt][lrow][loff]     = nv0;
            *(uint4*)&Vts[nxt][lrow][loff + 8] = nv1;
        }
        __syncthreads();   // single barrier per iteration
    }

    // epilogue: token = bx*64 + c, bx = 2*mb + (w>>1), c = (w&1)*32 + qg*16 + quad*4 + r
    const float g = gate[0];
    const int bx = 2*mb + (w >> 1);
    if (axis == 0) {
        #pragma unroll
        for (int qg = 0; qg < 2; ++qg)
            #pragma unroll
            for (int db = 0; db < 4; ++db) {
                const int d = db*16 + l16;                       // = h
                #pragma unroll
                for (int r = 0; r < 4; ++r) {
                    const int c = (w & 1)*32 + qg*16 + quad*4 + r;
                    atomicAdd(&dst[(((size_t)b*64 + d)*64 + bx)*64 + c], g * y[qg][db][r]);
                }
            }
    } else {
        #pragma unroll
        for (int qg = 0; qg < 2; ++qg)
            #pragma unroll
            for (int db = 0; db < 4; ++db) {
                const int d = db*16 + l16;                       // = w-coord
                const float pv = p[(b*64 + bx)*64 + d] * g;      // pixel (b, h=bx, w=d)
                #pragma unroll
                for (int r = 0; r < 4; ++r) {
                    const int c = (w & 1)*32 + qg*16 + quad*4 + r;
                    atomicAdd(&dst[(((size_t)b*64 + bx)*64 + d)*64 + c], pv * y[qg][db][r]);
                }
            }
    }
}

// fused: out = p * (feature + x1), with p computed inline (and stored for attn_w)
// p[pix] = conv_b + sum_nc (1 - sigmoid(predict[pix][nc])) * conv_w[nc]
__global__ __launch_bounds__(256) void prefill_kernel(
    const float* __restrict__ feature, const float* __restrict__ x1,
    const float* __restrict__ predict, const float* __restrict__ conv_w,
    const float* __restrict__ conv_b, float* __restrict__ p,
    float* __restrict__ out)
{
    const int i4 = blockIdx.x * 256 + threadIdx.x;    // 262144 float4s
    const int pix = i4 >> 4;                          // 16 threads share a pixel
    const float* row = predict + (size_t)pix * 19;
    float pv = conv_b[0];
    #pragma unroll
    for (int i = 0; i < 19; ++i) {
        float sg = __builtin_amdgcn_rcpf(1.0f + __builtin_exp2f(-1.442695041f * row[i]));
        pv += (1.0f - sg) * conv_w[i];
    }
    if ((i4 & 15) == 0) p[pix] = pv;                  // for attn width stage

    float4 f = ((const float4*)feature)[i4];
    float4 x = ((const float4*)x1)[i4];
    float4 o;
    o.x = pv * (f.x + x.x);
    o.y = pv * (f.y + x.y);
    o.z = pv * (f.z + x.z);
    o.w = pv * (f.w + x.w);
    ((float4*)out)[i4] = o;
}

extern "C" void kernel_launch(void* const* d_in, const int* in_sizes, int n_in,
                              void* d_out, int out_size, void* d_ws, size_t ws_size,
                              hipStream_t stream) {
    const float* feature = (const float*)d_in[0];
    const float* predict = (const float*)d_in[1];
    const float* hq_w = (const float*)d_in[2];
    const float* hq_b = (const float*)d_in[3];
    const float* hv_w = (const float*)d_in[4];
    const float* hv_b = (const float*)d_in[5];
    const float* wq_w = (const float*)d_in[6];
    const float* wq_b = (const float*)d_in[7];
    const float* wv_w = (const float*)d_in[8];
    const float* wv_b = (const float*)d_in[9];
    const float* h_gate = (const float*)d_in[10];
    const float* w_gate = (const float*)d_in[11];
    const float* conv_w = (const float*)d_in[12];
    const float* conv_b = (const float*)d_in[13];
    float* out = (float*)d_out;

    // workspace layout (8.06 MiB total)
    char* ws = (char*)d_ws;
    unsigned short* Qg  = (unsigned short*)(ws);                    // 2 MiB
    unsigned short* Vtg = (unsigned short*)(ws + (2u << 20));       // 2 MiB
    float*          x1  = (float*)(ws + (4u << 20));                // 4 MiB
    float*          p   = (float*)(ws + (8u << 20));                // 64 KiB

    dim3 blk(256);
    // height stage: Q/V from feature; also x1 = feature
    prep_kernel<<<dim3(64, 4), blk, 0, stream>>>(feature, hq_w, hq_b, hv_w, hv_b,
                                                 Qg, Vtg, x1, 4096, 64);
    // x1 += h_gate * Yh
    attn_kernel<<<dim3(32, 4, 4), blk, 0, stream>>>(Qg, Vtg, h_gate, x1, nullptr, 0);
    // width stage: Q/V from x1
    prep_kernel<<<dim3(64, 4), blk, 0, stream>>>(x1, wq_w, wq_b, wv_w, wv_b,
                                                 Qg, Vtg, nullptr, 64, 4096);
    // out = p * (feature + x1), p stored for attn_w
    prefill_kernel<<<dim3(1024), blk, 0, stream>>>(feature, x1, predict, conv_w,
                                                   conv_b, p, out);
    // out += p * w_gate * Yw
    attn_kernel<<<dim3(32, 4, 4), blk, 0, stream>>>(Qg, Vtg, w_gate, out, p, 1);
}

// Round 7
// 203.915 us; speedup vs baseline: 1.5373x; 1.3704x over previous
//
#include <hip/hip_runtime.h>

// bf16 MFMA fragment types (per guide §3)
typedef short bf16x8 __attribute__((ext_vector_type(8)));
typedef float f32x4  __attribute__((ext_vector_type(4)));

#define LDP 72  // padded bf16 LDS row (64 + 8 shorts): 144B stride, 16B-aligned

__device__ __forceinline__ unsigned short f2bf(float f) {
    union { float f; unsigned int u; } v; v.f = f;
    unsigned int r = v.u + 0x7fffu + ((v.u >> 16) & 1u);  // RNE, inputs never NaN
    return (unsigned short)(r >> 16);
}

__device__ __forceinline__ unsigned int pack_bf16(float a, float b) {
#if __has_builtin(__builtin_amdgcn_cvt_pk_bf16_f32)
    typedef __bf16 bf16x2 __attribute__((ext_vector_type(2)));
    bf16x2 p = __builtin_amdgcn_cvt_pk_bf16_f32(a, b);
    union { bf16x2 v; unsigned int u; } c; c.v = p;
    return c.u;
#else
    return (unsigned int)f2bf(a) | ((unsigned int)f2bf(b) << 16);
#endif
}

__device__ __forceinline__ float fast_sigmoid8(float x) {
    // sigmoid(x/8) = 1/(1+2^(x * -0.125*log2(e)))
    float e = __builtin_exp2f(x * -0.180336880f);
    return __builtin_amdgcn_rcpf(1.0f + e);
}

// ---------------------------------------------------------------------------
// prep: per (b, fixedIdx) block: slab[k][c] = src[b, ...], compute
//   Q[n=bx*64+c][j] -> Qg  [b][4096][64] bf16 (row-major)
//   V[n][j]         -> Vtg [b][64][4096] bf16 (transposed)
// height stage: bx=w, k=h (sK=4096,sF=64); width stage: bx=h, k=w (sK=64,sF=4096)
// ---------------------------------------------------------------------------
__global__ __launch_bounds__(256) void prep_kernel(
    const float* __restrict__ src,
    const float* __restrict__ wq, const float* __restrict__ bq,
    const float* __restrict__ wv, const float* __restrict__ bv,
    unsigned short* __restrict__ Qg, unsigned short* __restrict__ Vtg,
    float* __restrict__ x1out, int sK, int sF)
{
    __shared__ float slab[64][65];
    __shared__ float wqs[4096];
    __shared__ float wvs[4096];

    const int t  = threadIdx.x;
    const int bx = blockIdx.x, b = blockIdx.y;

    {   // stage weights
        const float4* wq4 = (const float4*)wq;
        const float4* wv4 = (const float4*)wv;
        float4* q4 = (float4*)wqs; float4* v4 = (float4*)wvs;
        #pragma unroll
        for (int i = 0; i < 4; ++i) {
            q4[i*256 + t] = wq4[i*256 + t];
            v4[i*256 + t] = wv4[i*256 + t];
        }
    }
    {   // stage slab
        const int k = t >> 2, c0 = (t & 3) << 4;
        const size_t sb = (size_t)b*262144 + (size_t)k*sK + (size_t)bx*sF + c0;
        #pragma unroll
        for (int i = 0; i < 4; ++i) {
            float4 v = *(const float4*)&src[sb + i*4];
            *(float4*)&slab[k][c0 + i*4] = v;
            if (x1out) *(float4*)&x1out[sb + i*4] = v;
        }
    }
    __syncthreads();

    const int c = t & 63, jg = t >> 6;
    float qa[16], va[16];
    #pragma unroll
    for (int jj = 0; jj < 16; ++jj) { qa[jj] = bq[jg*16+jj]; va[jj] = bv[jg*16+jj]; }
    for (int k = 0; k < 64; ++k) {
        const float xv = slab[k][c];
        const float* wqr = &wqs[k*64 + jg*16];
        const float* wvr = &wvs[k*64 + jg*16];
        #pragma unroll
        for (int jj = 0; jj < 16; ++jj) {
            qa[jj] += xv * wqr[jj];
            va[jj] += xv * wvr[jj];
        }
    }
    const int token = bx*64 + c;
    union { unsigned short s[16]; uint4 v[2]; } qp, vp;
    #pragma unroll
    for (int jj = 0; jj < 16; ++jj) { qp.s[jj] = f2bf(qa[jj]); vp.s[jj] = f2bf(va[jj]); }
    const size_t qoff = ((size_t)b*4096 + token)*64 + jg*16;
    *(uint4*)&Qg[qoff]     = qp.v[0];
    *(uint4*)&Qg[qoff + 8] = qp.v[1];
    #pragma unroll
    for (int jj = 0; jj < 16; ++jj)
        Vtg[((size_t)b*64 + jg*16 + jj)*4096 + token] = vp.s[jj];
}

// ---------------------------------------------------------------------------
// attn v7 = r3 core with switchable epilogue:
//   mode 2: plain coalesced dwordx4 partial stores -> P[ksplit][b][d][token]
//   mode 0/1: r3's atomicAdd fallback (only if ws_size too small)
// ---------------------------------------------------------------------------
__global__ __launch_bounds__(256) void attn_kernel(
    const unsigned short* __restrict__ Qg,
    const unsigned short* __restrict__ Vtg,
    const float* __restrict__ gate,
    float* __restrict__ dst,
    const float* __restrict__ p,
    int mode)
{
    __shared__ unsigned short Ksh[2][64][LDP];
    __shared__ unsigned short Vts[2][64][LDP];
    __shared__ unsigned int   Ss [64][LDP/2];

    const int t = threadIdx.x;
    const int mb = blockIdx.x, b = blockIdx.y, ksplit = blockIdx.z;
    const int lane = t & 63, w = t >> 6;
    const int quad = lane >> 4, l16 = lane & 15;

    const unsigned short* Qbase = Qg  + (size_t)b*262144;
    const unsigned short* Vbase = Vtg + (size_t)b*262144;

    // hoisted Q B-frags: B[k=d][n=query=l16]
    bf16x8 qb[2];
    {
        const unsigned short* qrow = Qbase + (size_t)(mb*64 + w*16 + l16)*64;
        qb[0] = *(const bf16x8*)&qrow[quad*8];
        qb[1] = *(const bf16x8*)&qrow[32 + quad*8];
    }

    f32x4 y[4];
    #pragma unroll
    for (int db = 0; db < 4; ++db) y[db] = (f32x4){0.f, 0.f, 0.f, 0.f};

    const int lrow = t >> 2, loff = (t & 3) << 4;
    const unsigned short* SsS = (const unsigned short*)&Ss[0][0];

    {   // prologue: stage tile 0 into buffer 0
        const int key0 = ksplit*1024;
        const uint4* gk = (const uint4*)(Qbase + (size_t)(key0 + lrow)*64 + loff);
        uint4 k0 = gk[0], k1 = gk[1];
        const uint4* gv = (const uint4*)(Vbase + (size_t)lrow*4096 + key0 + loff);
        uint4 v0 = gv[0], v1 = gv[1];
        *(uint4*)&Ksh[0][lrow][loff]     = k0;
        *(uint4*)&Ksh[0][lrow][loff + 8] = k1;
        *(uint4*)&Vts[0][lrow][loff]     = v0;
        *(uint4*)&Vts[0][lrow][loff + 8] = v1;
    }
    __syncthreads();

    for (int kb = 0; kb < 16; ++kb) {
        const int cur = kb & 1, nxt = cur ^ 1;

        // prefetch next tile into registers (clamped; stays in flight all iter)
        const int keyn = ksplit*1024 + (kb < 15 ? (kb + 1)*64 : kb*64);
        uint4 nk0, nk1, nv0, nv1;
        {
            const uint4* gk = (const uint4*)(Qbase + (size_t)(keyn + lrow)*64 + loff);
            nk0 = gk[0]; nk1 = gk[1];
            const uint4* gv = (const uint4*)(Vbase + (size_t)lrow*4096 + keyn + loff);
            nv0 = gv[0]; nv1 = gv[1];
        }

        // T_u = K_u · Q_w^T (A = K rows, B = Q rows); accumulate over d (s=0,1)
        f32x4 tacc[4];
        #pragma unroll
        for (int u = 0; u < 4; ++u) tacc[u] = (f32x4){0.f, 0.f, 0.f, 0.f};
        #pragma unroll
        for (int s = 0; s < 2; ++s) {
            #pragma unroll
            for (int u = 0; u < 4; ++u) {
                bf16x8 ka = *(const bf16x8*)&Ksh[cur][u*16 + l16][s*32 + quad*8];
                tacc[u] = __builtin_amdgcn_mfma_f32_16x16x32_bf16(ka, qb[s], tacc[u], 0,0,0);
            }
        }
        // lane holds T[key=u*16+quad*4+r][query=l16] -> sigmoid, pack, b64 store
        const int srow = w*16 + l16;
        #pragma unroll
        for (int u = 0; u < 4; ++u) {
            uint2 pk;
            pk.x = pack_bf16(fast_sigmoid8(tacc[u][0]), fast_sigmoid8(tacc[u][1]));
            pk.y = pack_bf16(fast_sigmoid8(tacc[u][2]), fast_sigmoid8(tacc[u][3]));
            *(uint2*)&Ss[srow][u*8 + quad*2] = pk;
        }
        // wave-private Ss rows: in-wave lgkmcnt ordering, no barrier needed

        // Y += S·V : A = S[m=query=l16][k=key], B = Vt rows
        #pragma unroll
        for (int s = 0; s < 2; ++s) {
            bf16x8 sa = *(const bf16x8*)&SsS[(size_t)(w*16 + l16)*LDP + s*32 + quad*8];
            #pragma unroll
            for (int db = 0; db < 4; ++db) {
                bf16x8 vb = *(const bf16x8*)&Vts[cur][db*16 + l16][s*32 + quad*8];
                y[db] = __builtin_amdgcn_mfma_f32_16x16x32_bf16(sa, vb, y[db], 0,0,0);
            }
        }

        // drain prefetch into the idle buffer
        if (kb < 15) {
            *(uint4*)&Ksh[nxt][lrow][loff]     = nk0;
            *(uint4*)&Ksh[nxt][lrow][loff + 8] = nk1;
            *(uint4*)&Vts[nxt][lrow][loff]     = nv0;
            *(uint4*)&Vts[nxt][lrow][loff + 8] = nv1;
        }
        __syncthreads();   // single barrier per iteration
    }

    if (mode == 2) {
        // partial store: P[ksplit][b][d][token], token = mb*64 + w*16 + quad*4 + r
        // slab per ksplit = 4b * 64d * 4096tok floats; y[db] r=0..3 consecutive
        float* Pp = dst + (((size_t)ksplit*4 + b) << 18);   // *64*4096 floats
        const int token0 = mb*64 + w*16 + quad*4;
        #pragma unroll
        for (int db = 0; db < 4; ++db) {
            const int d = db*16 + l16;
            *(float4*)&Pp[(size_t)d*4096 + token0] = *(float4*)&y[db];
        }
        return;
    }

    const float g = gate[0];
    if (mode == 0) {
        #pragma unroll
        for (int db = 0; db < 4; ++db) {
            const int d = db*16 + l16;                      // = h
            #pragma unroll
            for (int r = 0; r < 4; ++r) {
                const int tl = w*16 + quad*4 + r;           // = c (w-coord fixed = mb)
                atomicAdd(&dst[(((size_t)b*64 + d)*64 + mb)*64 + tl], g * y[db][r]);
            }
        }
    } else {
        #pragma unroll
        for (int db = 0; db < 4; ++db) {
            const int d = db*16 + l16;                      // = w-coord
            const float pv = p[(b*64 + mb)*64 + d] * g;     // h fixed = mb
            #pragma unroll
            for (int r = 0; r < 4; ++r) {
                const int tl = w*16 + quad*4 + r;           // = c
                atomicAdd(&dst[(((size_t)b*64 + mb)*64 + d)*64 + tl], pv * y[db][r]);
            }
        }
    }
}

// fold_h: x1 += g * (P0+P1+P2+P3).  P slab inner layout [b][d=h][token] == x1
// flat layout. 262144 float4s total; slab stride = 262144 float4s.
__global__ __launch_bounds__(256) void fold_h_kernel(
    float* __restrict__ x1, const float* __restrict__ P,
    const float* __restrict__ gate)
{
    const int i = blockIdx.x * 256 + threadIdx.x;    // [0, 262144)
    const float g = gate[0];
    const float4* P4 = (const float4*)P;
    float4 a  = P4[i];
    float4 b4 = P4[i +  262144];
    float4 c4 = P4[i +  524288];
    float4 d4 = P4[i +  786432];
    float4 x = ((float4*)x1)[i];
    x.x += g * (a.x + b4.x + c4.x + d4.x);
    x.y += g * (a.y + b4.y + c4.y + d4.y);
    x.z += g * (a.z + b4.z + c4.z + d4.z);
    x.w += g * (a.w + b4.w + c4.w + d4.w);
    ((float4*)x1)[i] = x;
}

// fold_w: out[b][h][w][c] += p[b,h,w]*g * sum_ks P[ks][b][d=w][token=h*64+c]
__global__ __launch_bounds__(256) void fold_w_kernel(
    float* __restrict__ out, const float* __restrict__ P,
    const float* __restrict__ p, const float* __restrict__ gate)
{
    const int i4 = blockIdx.x * 256 + threadIdx.x;   // [0, 262144) out float4s
    const int j = i4 << 2;                           // flat float index
    const int b = j >> 18, h = (j >> 12) & 63, d = (j >> 6) & 63, c = j & 63;
    const size_t pif4 = (((size_t)(b*64 + d) << 12) + h*64 + c) >> 2;
    const float4* P4 = (const float4*)P;
    float4 a  = P4[pif4];
    float4 b4 = P4[pif4 + 262144];
    float4 c4 = P4[pif4 + 524288];
    float4 d4 = P4[pif4 + 786432];
    const float pv = p[j >> 6] * gate[0];
    float4 o = ((float4*)out)[i4];
    o.x += pv * (a.x + b4.x + c4.x + d4.x);
    o.y += pv * (a.y + b4.y + c4.y + d4.y);
    o.z += pv * (a.z + b4.z + c4.z + d4.z);
    o.w += pv * (a.w + b4.w + c4.w + d4.w);
    ((float4*)out)[i4] = o;
}

// fused: out = p * (feature + x1), with p computed inline (stored for width fold)
__global__ __launch_bounds__(256) void prefill_kernel(
    const float* __restrict__ feature, const float* __restrict__ x1,
    const float* __restrict__ predict, const float* __restrict__ conv_w,
    const float* __restrict__ conv_b, float* __restrict__ p,
    float* __restrict__ out)
{
    const int i4 = blockIdx.x * 256 + threadIdx.x;    // 262144 float4s
    const int pix = i4 >> 4;                          // 16 threads share a pixel
    const float* row = predict + (size_t)pix * 19;
    float pv = conv_b[0];
    #pragma unroll
    for (int i = 0; i < 19; ++i) {
        float sg = __builtin_amdgcn_rcpf(1.0f + __builtin_exp2f(-1.442695041f * row[i]));
        pv += (1.0f - sg) * conv_w[i];
    }
    if ((i4 & 15) == 0) p[pix] = pv;

    float4 f = ((const float4*)feature)[i4];
    float4 x = ((const float4*)x1)[i4];
    float4 o;
    o.x = pv * (f.x + x.x);
    o.y = pv * (f.y + x.y);
    o.z = pv * (f.z + x.z);
    o.w = pv * (f.w + x.w);
    ((float4*)out)[i4] = o;
}

extern "C" void kernel_launch(void* const* d_in, const int* in_sizes, int n_in,
                              void* d_out, int out_size, void* d_ws, size_t ws_size,
                              hipStream_t stream) {
    const float* feature = (const float*)d_in[0];
    const float* predict = (const float*)d_in[1];
    const float* hq_w = (const float*)d_in[2];
    const float* hq_b = (const float*)d_in[3];
    const float* hv_w = (const float*)d_in[4];
    const float* hv_b = (const float*)d_in[5];
    const float* wq_w = (const float*)d_in[6];
    const float* wq_b = (const float*)d_in[7];
    const float* wv_w = (const float*)d_in[8];
    const float* wv_b = (const float*)d_in[9];
    const float* h_gate = (const float*)d_in[10];
    const float* w_gate = (const float*)d_in[11];
    const float* conv_w = (const float*)d_in[12];
    const float* conv_b = (const float*)d_in[13];
    float* out = (float*)d_out;

    // workspace layout
    char* ws = (char*)d_ws;
    unsigned short* Qg  = (unsigned short*)(ws);                        // 2 MiB
    unsigned short* Vtg = (unsigned short*)(ws + (2u << 20));           // 2 MiB
    float*          x1  = (float*)(ws + (4u << 20));                    // 4 MiB
    float*          p   = (float*)(ws + (8u << 20));                    // 64 KiB
    float*          P   = (float*)(ws + (8u << 20) + (128u << 10));     // 16 MiB partials
    const bool usePartials = ws_size >= ((8u << 20) + (128u << 10) + (16u << 20));

    dim3 blk(256);
    // height stage: Q/V from feature; also x1 = feature
    prep_kernel<<<dim3(64, 4), blk, 0, stream>>>(feature, hq_w, hq_b, hv_w, hv_b,
                                                 Qg, Vtg, x1, 4096, 64);
    if (usePartials) {
        attn_kernel<<<dim3(64, 4, 4), blk, 0, stream>>>(Qg, Vtg, h_gate, P, nullptr, 2);
        fold_h_kernel<<<dim3(1024), blk, 0, stream>>>(x1, P, h_gate);
    } else {
        attn_kernel<<<dim3(64, 4, 4), blk, 0, stream>>>(Qg, Vtg, h_gate, x1, nullptr, 0);
    }
    // width stage: Q/V from x1
    prep_kernel<<<dim3(64, 4), blk, 0, stream>>>(x1, wq_w, wq_b, wv_w, wv_b,
                                                 Qg, Vtg, nullptr, 64, 4096);
    // out = p * (feature + x1), p stored for the width fold
    prefill_kernel<<<dim3(1024), blk, 0, stream>>>(feature, x1, predict, conv_w,
                                                   conv_b, p, out);
    if (usePartials) {
        attn_kernel<<<dim3(64, 4, 4), blk, 0, stream>>>(Qg, Vtg, w_gate, P, nullptr, 2);
        fold_w_kernel<<<dim3(1024), blk, 0, stream>>>(out, P, p, w_gate);
    } else {
        attn_kernel<<<dim3(64, 4, 4), blk, 0, stream>>>(Qg, Vtg, w_gate, out, p, 1);
    }
}

// Round 8
// 203.466 us; speedup vs baseline: 1.5407x; 1.0022x over previous
//
#include <hip/hip_runtime.h>

// MFMA fragment types
typedef short bf16x8 __attribute__((ext_vector_type(8)));
typedef float f32x16 __attribute__((ext_vector_type(16)));

__device__ __forceinline__ unsigned short f2bf(float f) {
    union { float f; unsigned int u; } v; v.f = f;
    unsigned int r = v.u + 0x7fffu + ((v.u >> 16) & 1u);  // RNE, inputs never NaN
    return (unsigned short)(r >> 16);
}

__device__ __forceinline__ unsigned int pack_bf16(float a, float b) {
#if __has_builtin(__builtin_amdgcn_cvt_pk_bf16_f32)
    typedef __bf16 bf16x2 __attribute__((ext_vector_type(2)));
    bf16x2 p = __builtin_amdgcn_cvt_pk_bf16_f32(a, b);
    union { bf16x2 v; unsigned int u; } c; c.v = p;
    return c.u;
#else
    return (unsigned int)f2bf(a) | ((unsigned int)f2bf(b) << 16);
#endif
}

__device__ __forceinline__ float fast_sigmoid8(float x) {
    // sigmoid(x/8) = 1/(1+2^(x * -0.125*log2(e)))
    float e = __builtin_exp2f(x * -0.180336880f);
    return __builtin_amdgcn_rcpf(1.0f + e);
}

// ---------------------------------------------------------------------------
// prep (height stage): per (b, bx=w) block: slab[k=h][c] = feature[b,h,w,c],
//   Q -> Qg [b][4096][64] bf16 row-major ; V -> Vtg [b][64][4096] bf16 (T)
// ---------------------------------------------------------------------------
__global__ __launch_bounds__(256) void prep_kernel(
    const float* __restrict__ src,
    const float* __restrict__ wq, const float* __restrict__ bq,
    const float* __restrict__ wv, const float* __restrict__ bv,
    unsigned short* __restrict__ Qg, unsigned short* __restrict__ Vtg)
{
    __shared__ float slab[64][65];
    __shared__ float wqs[4096];
    __shared__ float wvs[4096];

    const int t  = threadIdx.x;
    const int bx = blockIdx.x, b = blockIdx.y;

    {   // stage weights
        const float4* wq4 = (const float4*)wq;
        const float4* wv4 = (const float4*)wv;
        float4* q4 = (float4*)wqs; float4* v4 = (float4*)wvs;
        #pragma unroll
        for (int i = 0; i < 4; ++i) {
            q4[i*256 + t] = wq4[i*256 + t];
            v4[i*256 + t] = wv4[i*256 + t];
        }
    }
    {   // stage slab: k=h rows (stride 4096), bx=w fixed
        const int k = t >> 2, c0 = (t & 3) << 4;
        const size_t sb = (size_t)b*262144 + (size_t)k*4096 + (size_t)bx*64 + c0;
        #pragma unroll
        for (int i = 0; i < 4; ++i)
            *(float4*)&slab[k][c0 + i*4] = *(const float4*)&src[sb + i*4];
    }
    __syncthreads();

    const int c = t & 63, jg = t >> 6;
    float qa[16], va[16];
    #pragma unroll
    for (int jj = 0; jj < 16; ++jj) { qa[jj] = bq[jg*16+jj]; va[jj] = bv[jg*16+jj]; }
    for (int k = 0; k < 64; ++k) {
        const float xv = slab[k][c];
        const float* wqr = &wqs[k*64 + jg*16];
        const float* wvr = &wvs[k*64 + jg*16];
        #pragma unroll
        for (int jj = 0; jj < 16; ++jj) {
            qa[jj] += xv * wqr[jj];
            va[jj] += xv * wvr[jj];
        }
    }
    const int token = bx*64 + c;
    union { unsigned short s[16]; uint4 v[2]; } qp, vp;
    #pragma unroll
    for (int jj = 0; jj < 16; ++jj) { qp.s[jj] = f2bf(qa[jj]); vp.s[jj] = f2bf(va[jj]); }
    const size_t qoff = ((size_t)b*4096 + token)*64 + jg*16;
    *(uint4*)&Qg[qoff]     = qp.v[0];
    *(uint4*)&Qg[qoff + 8] = qp.v[1];
    #pragma unroll
    for (int jj = 0; jj < 16; ++jj)
        Vtg[((size_t)b*64 + jg*16 + jj)*4096 + token] = vp.s[jj];
}

// ---------------------------------------------------------------------------
// prep_w (width stage) FUSED with fold_h:
//   x1[b,h,w,c] = feature + g*(P0+P1+P2+P3)   (computed during slab staging,
//   written to x1out for the final kernel), then same Q/V GEMM.
//   Block (bx=h, b); slab[k=w][c]; token = h*64 + c.
// ---------------------------------------------------------------------------
__global__ __launch_bounds__(256) void prep_w_kernel(
    const float* __restrict__ feature, const float* __restrict__ Pin,
    const float* __restrict__ gate,
    const float* __restrict__ wq, const float* __restrict__ bq,
    const float* __restrict__ wv, const float* __restrict__ bv,
    unsigned short* __restrict__ Qg, unsigned short* __restrict__ Vtg,
    float* __restrict__ x1out)
{
    __shared__ float slab[64][65];
    __shared__ float wqs[4096];
    __shared__ float wvs[4096];

    const int t  = threadIdx.x;
    const int bx = blockIdx.x, b = blockIdx.y;   // bx = h

    {   // stage weights
        const float4* wq4 = (const float4*)wq;
        const float4* wv4 = (const float4*)wv;
        float4* q4 = (float4*)wqs; float4* v4 = (float4*)wvs;
        #pragma unroll
        for (int i = 0; i < 4; ++i) {
            q4[i*256 + t] = wq4[i*256 + t];
            v4[i*256 + t] = wv4[i*256 + t];
        }
    }
    {   // stage slab with inline fold: P_h[ks][b][d=h][token=w*64+c]
        const int k = t >> 2, c0 = (t & 3) << 4;
        const size_t off = (size_t)bx*4096 + (size_t)k*64 + c0;  // h*4096 + w*64 + c
        const size_t fb  = (size_t)b*262144 + off;
        const float g = gate[0];
        #pragma unroll
        for (int i = 0; i < 4; ++i) {
            float4 v  = *(const float4*)&feature[fb + i*4];
            float4 p0 = *(const float4*)&Pin[((size_t)(b     ) << 18) + off + i*4];
            float4 p1 = *(const float4*)&Pin[((size_t)(b +  4) << 18) + off + i*4];
            float4 p2 = *(const float4*)&Pin[((size_t)(b +  8) << 18) + off + i*4];
            float4 p3 = *(const float4*)&Pin[((size_t)(b + 12) << 18) + off + i*4];
            v.x += g * (p0.x + p1.x + p2.x + p3.x);
            v.y += g * (p0.y + p1.y + p2.y + p3.y);
            v.z += g * (p0.z + p1.z + p2.z + p3.z);
            v.w += g * (p0.w + p1.w + p2.w + p3.w);
            *(float4*)&slab[k][c0 + i*4] = v;
            *(float4*)&x1out[fb + i*4] = v;
        }
    }
    __syncthreads();

    const int c = t & 63, jg = t >> 6;
    float qa[16], va[16];
    #pragma unroll
    for (int jj = 0; jj < 16; ++jj) { qa[jj] = bq[jg*16+jj]; va[jj] = bv[jg*16+jj]; }
    for (int k = 0; k < 64; ++k) {
        const float xv = slab[k][c];
        const float* wqr = &wqs[k*64 + jg*16];
        const float* wvr = &wvs[k*64 + jg*16];
        #pragma unroll
        for (int jj = 0; jj < 16; ++jj) {
            qa[jj] += xv * wqr[jj];
            va[jj] += xv * wvr[jj];
        }
    }
    const int token = bx*64 + c;
    union { unsigned short s[16]; uint4 v[2]; } qp, vp;
    #pragma unroll
    for (int jj = 0; jj < 16; ++jj) { qp.s[jj] = f2bf(qa[jj]); vp.s[jj] = f2bf(va[jj]); }
    const size_t qoff = ((size_t)b*4096 + token)*64 + jg*16;
    *(uint4*)&Qg[qoff]     = qp.v[0];
    *(uint4*)&Qg[qoff + 8] = qp.v[1];
    #pragma unroll
    for (int jj = 0; jj < 16; ++jj)
        Vtg[((size_t)b*64 + jg*16 + jj)*4096 + token] = vp.s[jj];
}

// ---------------------------------------------------------------------------
// attn v8: 32x32x16 MFMA. Block = 4 waves = 128 queries; 16 key-tiles of 64,
// ksplit=4. Wave owns 32 queries. Per iter: T = K·Q^T (2 tiles of 32x32,
// 4 k-steps over d) -> sigmoid -> wave-private Ss rows (b64 packed) ->
// Y += S·V (2 d-tiles, 4 k-steps over keys). Single-buffer LDS staging,
// register prefetch, 2 barriers/iter. Epilogue: plain partial stores to
// P[ksplit][b][d][token].
// C/D layout (verified m74/m101): col=lane&31, row=(reg&3)+8*(reg>>2)+4*(lane>>5)
// A: m=lane&31, k=(lane>>5)*8+j ; B: n=lane&31, k=(lane>>5)*8+j
// ---------------------------------------------------------------------------
__global__ __launch_bounds__(256) void attn_kernel(
    const unsigned short* __restrict__ Qg,
    const unsigned short* __restrict__ Vtg,
    float* __restrict__ P)
{
    __shared__ unsigned short Ksh[64][72];
    __shared__ unsigned short Vts[64][72];
    __shared__ unsigned short Ss[128][72];   // rows wave-private (w*32+l32)

    const int t = threadIdx.x;
    const int mb = blockIdx.x, b = blockIdx.y, ksplit = blockIdx.z;
    const int lane = t & 63, w = t >> 6;
    const int l32 = lane & 31, hi = lane >> 5;

    const unsigned short* Qbase = Qg  + (size_t)b*262144;
    const unsigned short* Vbase = Vtg + (size_t)b*262144;

    // Q B-frags: n=query=l32, k=d = s*16 + hi*8 + j
    bf16x8 qb[4];
    {
        const unsigned short* qrow = Qbase + (size_t)(mb*128 + w*32 + l32)*64 + hi*8;
        qb[0] = *(const bf16x8*)(qrow);
        qb[1] = *(const bf16x8*)(qrow + 16);
        qb[2] = *(const bf16x8*)(qrow + 32);
        qb[3] = *(const bf16x8*)(qrow + 48);
    }

    f32x16 y[2];
    #pragma unroll
    for (int i = 0; i < 16; ++i) { y[0][i] = 0.f; y[1][i] = 0.f; }

    // staging addressing: thread t stages row lrow, two 16B chunks
    const int lrow = t >> 2;
    const int loff = (t & 3) << 4;   // shorts
    {   // prologue: stage tile 0
        const int key0 = ksplit*1024;
        const uint4* gk = (const uint4*)(Qbase + (size_t)(key0 + lrow)*64 + loff);
        uint4 k0 = gk[0], k1 = gk[1];
        const uint4* gv = (const uint4*)(Vbase + (size_t)lrow*4096 + key0 + loff);
        uint4 v0 = gv[0], v1 = gv[1];
        *(uint4*)&Ksh[lrow][loff]     = k0;
        *(uint4*)&Ksh[lrow][loff + 8] = k1;
        *(uint4*)&Vts[lrow][loff]     = v0;
        *(uint4*)&Vts[lrow][loff + 8] = v1;
    }
    __syncthreads();

    unsigned short* srowS = &Ss[w*32 + l32][0];
    unsigned int*   srowU = (unsigned int*)srowS;

    for (int kb = 0; kb < 16; ++kb) {
        // prefetch next tile into registers (in flight across compute phase)
        uint4 nk0 = {0,0,0,0}, nk1 = {0,0,0,0}, nv0 = {0,0,0,0}, nv1 = {0,0,0,0};
        if (kb < 15) {
            const int keyn = ksplit*1024 + (kb + 1)*64;
            const uint4* gk = (const uint4*)(Qbase + (size_t)(keyn + lrow)*64 + loff);
            nk0 = gk[0]; nk1 = gk[1];
            const uint4* gv = (const uint4*)(Vbase + (size_t)lrow*4096 + keyn + loff);
            nv0 = gv[0]; nv1 = gv[1];
        }

        // T = K·Q^T : tt[u] covers keys u*32..+32 for this wave's 32 queries
        f32x16 tt[2];
        #pragma unroll
        for (int i = 0; i < 16; ++i) { tt[0][i] = 0.f; tt[1][i] = 0.f; }
        #pragma unroll
        for (int s = 0; s < 4; ++s) {
            const int co = s*16 + hi*8;
            bf16x8 ka0 = *(const bf16x8*)&Ksh[l32][co];
            bf16x8 ka1 = *(const bf16x8*)&Ksh[32 + l32][co];
            tt[0] = __builtin_amdgcn_mfma_f32_32x32x16_bf16(ka0, qb[s], tt[0], 0,0,0);
            tt[1] = __builtin_amdgcn_mfma_f32_32x32x16_bf16(ka1, qb[s], tt[1], 0,0,0);
        }

        // sigmoid + pack: lane holds T[key=u*32+8g+4hi+e][query=l32], e=0..3
        #pragma unroll
        for (int u = 0; u < 2; ++u)
            #pragma unroll
            for (int g = 0; g < 4; ++g) {
                uint2 pk;
                pk.x = pack_bf16(fast_sigmoid8(tt[u][4*g+0]), fast_sigmoid8(tt[u][4*g+1]));
                pk.y = pack_bf16(fast_sigmoid8(tt[u][4*g+2]), fast_sigmoid8(tt[u][4*g+3]));
                *(uint2*)&srowU[u*16 + g*4 + hi*2] = pk;
            }
        // wave-private rows: in-wave lgkmcnt ordering, no barrier for round-trip

        // Y += S·V : A = S[q=l32][key], B[k=key][n=d] from Vt rows
        #pragma unroll
        for (int ks = 0; ks < 4; ++ks) {
            const int co = ks*16 + hi*8;
            bf16x8 sa  = *(const bf16x8*)&srowS[co];
            bf16x8 vb0 = *(const bf16x8*)&Vts[l32][co];
            bf16x8 vb1 = *(const bf16x8*)&Vts[32 + l32][co];
            y[0] = __builtin_amdgcn_mfma_f32_32x32x16_bf16(sa, vb0, y[0], 0,0,0);
            y[1] = __builtin_amdgcn_mfma_f32_32x32x16_bf16(sa, vb1, y[1], 0,0,0);
        }

        __syncthreads();   // all waves done reading current tile
        if (kb < 15) {
            *(uint4*)&Ksh[lrow][loff]     = nk0;
            *(uint4*)&Ksh[lrow][loff + 8] = nk1;
            *(uint4*)&Vts[lrow][loff]     = nv0;
            *(uint4*)&Vts[lrow][loff + 8] = nv1;
        }
        __syncthreads();   // next tile visible
    }

    // epilogue: P[ksplit][b][d][token]; token = mb*128 + w*32 + 8g + 4hi + e
    float* Pp = P + (((size_t)(ksplit*4 + b)) << 18);
    const int token0 = mb*128 + w*32 + hi*4;
    #pragma unroll
    for (int dt = 0; dt < 2; ++dt) {
        const int d = dt*32 + l32;
        #pragma unroll
        for (int g = 0; g < 4; ++g) {
            float4 v;
            v.x = y[dt][4*g+0]; v.y = y[dt][4*g+1];
            v.z = y[dt][4*g+2]; v.w = y[dt][4*g+3];
            *(float4*)&Pp[(size_t)d*4096 + token0 + 8*g] = v;
        }
    }
}

// ---------------------------------------------------------------------------
// final: out = p * (feature + x1 + g*sum_ks P_w[ks][b][d=w][token=h*64+c])
// with p computed inline from predict (1x1 conv of 1-sigmoid).
// ---------------------------------------------------------------------------
__global__ __launch_bounds__(256) void final_kernel(
    const float* __restrict__ feature, const float* __restrict__ x1,
    const float* __restrict__ Pin, const float* __restrict__ predict,
    const float* __restrict__ conv_w, const float* __restrict__ conv_b,
    const float* __restrict__ gate, float* __restrict__ out)
{
    const int i4 = blockIdx.x * 256 + threadIdx.x;   // [0, 262144)
    const int j = i4 << 2;
    const int pix = j >> 6;
    const float* row = predict + (size_t)pix * 19;
    float pv = conv_b[0];
    #pragma unroll
    for (int i = 0; i < 19; ++i) {
        float sg = __builtin_amdgcn_rcpf(1.0f + __builtin_exp2f(-1.442695041f * row[i]));
        pv += (1.0f - sg) * conv_w[i];
    }

    const int b = j >> 18, h = (j >> 12) & 63, d = (j >> 6) & 63, c = j & 63;
    const size_t pif4 = (((size_t)(b*64 + d) << 12) + h*64 + c) >> 2;
    const float4* P4 = (const float4*)Pin;
    float4 a  = P4[pif4];
    float4 b4 = P4[pif4 + 262144];
    float4 c4 = P4[pif4 + 524288];
    float4 d4 = P4[pif4 + 786432];
    const float g = gate[0];
    float4 f = ((const float4*)feature)[i4];
    float4 x = ((const float4*)x1)[i4];
    float4 o;
    o.x = pv * (f.x + x.x + g * (a.x + b4.x + c4.x + d4.x));
    o.y = pv * (f.y + x.y + g * (a.y + b4.y + c4.y + d4.y));
    o.z = pv * (f.z + x.z + g * (a.z + b4.z + c4.z + d4.z));
    o.w = pv * (f.w + x.w + g * (a.w + b4.w + c4.w + d4.w));
    ((float4*)out)[i4] = o;
}

extern "C" void kernel_launch(void* const* d_in, const int* in_sizes, int n_in,
                              void* d_out, int out_size, void* d_ws, size_t ws_size,
                              hipStream_t stream) {
    const float* feature = (const float*)d_in[0];
    const float* predict = (const float*)d_in[1];
    const float* hq_w = (const float*)d_in[2];
    const float* hq_b = (const float*)d_in[3];
    const float* hv_w = (const float*)d_in[4];
    const float* hv_b = (const float*)d_in[5];
    const float* wq_w = (const float*)d_in[6];
    const float* wq_b = (const float*)d_in[7];
    const float* wv_w = (const float*)d_in[8];
    const float* wv_b = (const float*)d_in[9];
    const float* h_gate = (const float*)d_in[10];
    const float* w_gate = (const float*)d_in[11];
    const float* conv_w = (const float*)d_in[12];
    const float* conv_b = (const float*)d_in[13];
    float* out = (float*)d_out;

    // workspace layout: Qg 2MB | Vtg 2MB | x1 4MB | P 16MB  (= 24 MiB)
    char* ws = (char*)d_ws;
    unsigned short* Qg  = (unsigned short*)(ws);
    unsigned short* Vtg = (unsigned short*)(ws + (2u << 20));
    float*          x1  = (float*)(ws + (4u << 20));
    float*          P   = (float*)(ws + (8u << 20));

    dim3 blk(256);
    // height stage
    prep_kernel<<<dim3(64, 4), blk, 0, stream>>>(feature, hq_w, hq_b, hv_w, hv_b,
                                                 Qg, Vtg);
    attn_kernel<<<dim3(32, 4, 4), blk, 0, stream>>>(Qg, Vtg, P);
    // width stage: x1 = feature + h_gate*sum(P) computed inline
    prep_w_kernel<<<dim3(64, 4), blk, 0, stream>>>(feature, P, h_gate,
                                                   wq_w, wq_b, wv_w, wv_b,
                                                   Qg, Vtg, x1);
    attn_kernel<<<dim3(32, 4, 4), blk, 0, stream>>>(Qg, Vtg, P);
    // out = p * (feature + x1 + w_gate*sum(P))
    final_kernel<<<dim3(1024), blk, 0, stream>>>(feature, x1, P, predict,
                                                 conv_w, conv_b, w_gate, out);
}